// Round 4
// baseline (56.223 us; speedup 1.0000x reference)
//
#include <hip/hip_runtime.h>

#define VOCAB 30522
#define D     768
#define NC    9
#define NROWS 16384          // 32*512
#define TPB   256

#define G_ROW 512            // 4 waves/block * 8 rows/wave * 512 = 16384 rows
#define RPW   8

#define G_FIN 256
#define SLICE 120            // 256 * 120 = 30720 >= VOCAB

typedef float v2f __attribute__((ext_vector_type(2)));

// ---------------------------------------------------------------------------
// Full-wave (64-lane) sum via DPP — pure VALU. Result valid in lane 63.
// (Sequence numerically validated rounds 2-3.)
// ---------------------------------------------------------------------------
__device__ __forceinline__ float wave_reduce_add(float x) {
#define DPP_STEP(ctrl)                                                         \
    do {                                                                       \
        int t_ = __builtin_amdgcn_update_dpp(0, __float_as_int(x), (ctrl),     \
                                             0xf, 0xf, true);                  \
        x += __int_as_float(t_);                                               \
    } while (0)
    DPP_STEP(0x111); // row_shr:1
    DPP_STEP(0x112); // row_shr:2
    DPP_STEP(0x114); // row_shr:4
    DPP_STEP(0x118); // row_shr:8
    DPP_STEP(0x142); // row_bcast:15
    DPP_STEP(0x143); // row_bcast:31 -> lane63 = total
#undef DPP_STEP
    return x;
}

// wsum2[c] = sum_{d>=768} W[d,c].  256 threads (4 waves); lane-63 writes.
__device__ __forceinline__ void compute_wsum2(const float* __restrict__ W,
                                              int lane, int wave, float* dst) {
    float s0 = 0.f, s1 = 0.f, s2 = 0.f;
    #pragma unroll
    for (int k = 0; k < 12; ++k) {
        const float* rw = W + (size_t)(D + lane + 64 * k) * NC;
        s0 += rw[wave];
        s1 += rw[wave + 4];
        if (wave == 0) s2 += rw[8];
    }
    s0 = wave_reduce_add(s0);
    s1 = wave_reduce_add(s1);
    s2 = wave_reduce_add(s2);
    if (lane == 63) {
        dst[wave]     = s0;
        dst[wave + 4] = s1;
        if (wave == 0) dst[8] = s2;
    }
}

// FMA one 4-dim chunk: v = h values for dims d..d+3; wk[j][p] = W'[d+j] column
// pair p (cols 2p,2p+1; p=4 -> {col8, ones}).  acc pairs accumulate 9 dots +
// the row sum (ones column).
__device__ __forceinline__ void fma4(v2f (&acc)[5], float4 v,
                                     const v2f (&wk)[4][5]) {
    const float vv[4] = {v.x, v.y, v.z, v.w};
    #pragma unroll
    for (int j = 0; j < 4; ++j) {
        const v2f b = {vv[j], vv[j]};
        #pragma unroll
        for (int p = 0; p < 5; ++p)
            acc[p] = __builtin_elementwise_fma(b, wk[j][p], acc[p]);
    }
}

// ---------------------------------------------------------------------------
// Row pass: wave per row, 8 rows/wave, 2-row compute with depth-1 prefetch of
// the next pair's 6 float4 loads (h latency hides under current compute).
// No atomics: writes 9 dots -> out, row mean -> means[].
// ---------------------------------------------------------------------------
__global__ __launch_bounds__(TPB, 2) void row_kernel(
    const float* __restrict__ h, const float* __restrict__ W,
    float* __restrict__ means, float* __restrict__ out)
{
    const int lane = threadIdx.x & 63;
    const int wave = threadIdx.x >> 6;
    const int base = (blockIdx.x * 4 + wave) * RPW;

    // W' (with ones column) for this lane's 12 dims: 27 coalesced float4.
    v2f wf[3][4][5];
    #pragma unroll
    for (int k = 0; k < 3; ++k) {
        const float4* wp = (const float4*)W + (size_t)(lane + 64 * k) * 9;
        float w36[36];
        #pragma unroll
        for (int i = 0; i < 9; ++i) {
            float4 v = wp[i];
            w36[4*i+0] = v.x; w36[4*i+1] = v.y; w36[4*i+2] = v.z; w36[4*i+3] = v.w;
        }
        #pragma unroll
        for (int j = 0; j < 4; ++j) {
            #pragma unroll
            for (int p = 0; p < 4; ++p)
                wf[k][j][p] = (v2f){w36[j*9 + 2*p], w36[j*9 + 2*p + 1]};
            wf[k][j][4] = (v2f){w36[j*9 + 8], 1.0f};
        }
    }

    const float4* hb = (const float4*)h + (size_t)base * (D / 4) + lane;
#define LDROW(rr, V0, V1, V2)                                                  \
    do { const float4* hp_ = hb + (size_t)(rr) * (D / 4);                      \
         V0 = hp_[0]; V1 = hp_[64]; V2 = hp_[128]; } while (0)

    float4 A0, A1, A2, B0, B1, B2;
    LDROW(0, A0, A1, A2);
    LDROW(1, B0, B1, B2);

    #pragma unroll
    for (int rp = 0; rp < RPW / 2; ++rp) {
        float4 N0, N1, N2, M0, M1, M2;
        if (rp < RPW / 2 - 1) {
            LDROW(2 * rp + 2, N0, N1, N2);
            LDROW(2 * rp + 3, M0, M1, M2);
        }
        const int rA = base + 2 * rp, rB = rA + 1;

        v2f accA[5], accB[5];
        #pragma unroll
        for (int p = 0; p < 5; ++p) {
            accA[p] = (v2f){0.f, 0.f};
            accB[p] = (v2f){0.f, 0.f};
        }
        fma4(accA, A0, wf[0]); fma4(accA, A1, wf[1]); fma4(accA, A2, wf[2]);
        fma4(accB, B0, wf[0]); fma4(accB, B1, wf[1]); fma4(accB, B2, wf[2]);

        float ra[10] = {accA[0].x, accA[0].y, accA[1].x, accA[1].y, accA[2].x,
                        accA[2].y, accA[3].x, accA[3].y, accA[4].x, accA[4].y};
        float rb[10] = {accB[0].x, accB[0].y, accB[1].x, accB[1].y, accB[2].x,
                        accB[2].y, accB[3].x, accB[3].y, accB[4].x, accB[4].y};
        // Interleave the two reduction chains for ILP across DPP latency.
        #pragma unroll
        for (int t = 0; t < 10; ++t) {
            ra[t] = wave_reduce_add(ra[t]);
            rb[t] = wave_reduce_add(rb[t]);
        }

        if (lane == 63) {
            float* oA = out + (size_t)rA * NC;
            float* oB = out + (size_t)rB * NC;
            #pragma unroll
            for (int c = 0; c < 9; ++c) { oA[c] = ra[c]; oB[c] = rb[c]; }
            means[rA] = ra[9] * (1.f / 768.f);
            means[rB] = rb[9] * (1.f / 768.f);
        }

        if (rp < RPW / 2 - 1) {
            A0 = N0; A1 = N1; A2 = N2;
            B0 = M0; B1 = M1; B2 = M2;
        }
    }
#undef LDROW
}

// ---------------------------------------------------------------------------
// Finalize: block b owns vocab slice [b*SLICE, b*SLICE+SLICE).
//   scan 1: build slice sum/cnt in LDS from the 16384 (id, mean) pairs.
//   scan 2: rows whose id is in the slice get out[row,:] += ctx*wsum2 + bias.
// Every id lies in exactly one slice -> each row finalized exactly once.
// ---------------------------------------------------------------------------
__global__ __launch_bounds__(TPB) void finalize_kernel(
    const int* __restrict__ ids, const float* __restrict__ means,
    const float* __restrict__ W, const float* __restrict__ bias,
    float* __restrict__ out)
{
    __shared__ float s_sum[SLICE];
    __shared__ float s_cnt[SLICE];
    __shared__ float s_wsum2[NC];

    const int tid  = threadIdx.x;
    const int lane = tid & 63;
    const int wave = tid >> 6;
    const int lo   = blockIdx.x * SLICE;

    for (int i = tid; i < SLICE; i += TPB) { s_sum[i] = 0.f; s_cnt[i] = 0.f; }
    compute_wsum2(W, lane, wave, s_wsum2);
    __syncthreads();

    for (int p = tid; p < NROWS; p += TPB) {
        const int k = ids[p] - lo;
        if ((unsigned)k < (unsigned)SLICE) {
            atomicAdd(&s_sum[k], means[p]);
            atomicAdd(&s_cnt[k], 1.f);
        }
    }
    __syncthreads();

    for (int p = tid; p < NROWS; p += TPB) {
        const int k = ids[p] - lo;
        if ((unsigned)k < (unsigned)SLICE) {
            const float ctx = s_sum[k] / fmaxf(s_cnt[k], 1.f);
            float* op = out + (size_t)p * NC;
            #pragma unroll
            for (int c = 0; c < 9; ++c)
                op[c] += ctx * s_wsum2[c] + bias[c];
        }
    }
}

extern "C" void kernel_launch(void* const* d_in, const int* in_sizes, int n_in,
                              void* d_out, int out_size, void* d_ws, size_t ws_size,
                              hipStream_t stream) {
    const int*   ids = (const int*)  d_in[0];  // [32,512] int32
    const float* h   = (const float*)d_in[1];  // [32,512,768] f32
    const float* W   = (const float*)d_in[2];  // [1536,9] f32
    const float* b   = (const float*)d_in[3];  // [9] f32
    float* out   = (float*)d_out;              // [32,512,9] f32
    float* means = (float*)d_ws;               // [16384] f32 (64 KB of ws)

    row_kernel<<<G_ROW, TPB, 0, stream>>>(h, W, means, out);
    finalize_kernel<<<G_FIN, TPB, 0, stream>>>(ids, means, W, b, out);
}

// Round 5
// 27.554 us; speedup vs baseline: 2.0405x; 2.0405x over previous
//
#include <hip/hip_runtime.h>

#define VOCAB 30522
#define D     768
#define NC    9
#define NROWS 16384          // 32*512
#define TPB   256

#define G_ROW 512            // 4 waves/block * 8 rows/wave * 512 = 16384 rows
#define RPW   8

#define G_FIN   512
#define TPB_FIN 1024
#define SLICE   60           // 512 * 60 = 30720 >= VOCAB

typedef float v2f __attribute__((ext_vector_type(2)));

// ---------------------------------------------------------------------------
// Full-wave (64-lane) sum via DPP — pure VALU. Result valid in lane 63.
// (Sequence numerically validated rounds 2-4.)
// ---------------------------------------------------------------------------
__device__ __forceinline__ float wave_reduce_add(float x) {
#define DPP_STEP(ctrl)                                                         \
    do {                                                                       \
        int t_ = __builtin_amdgcn_update_dpp(0, __float_as_int(x), (ctrl),     \
                                             0xf, 0xf, true);                  \
        x += __int_as_float(t_);                                               \
    } while (0)
    DPP_STEP(0x111); // row_shr:1
    DPP_STEP(0x112); // row_shr:2
    DPP_STEP(0x114); // row_shr:4
    DPP_STEP(0x118); // row_shr:8
    DPP_STEP(0x142); // row_bcast:15
    DPP_STEP(0x143); // row_bcast:31 -> lane63 = total
#undef DPP_STEP
    return x;
}

// wsum2[c] = sum_{d>=768} W[d,c].  Uses waves 0..3 (lane-63 writes).
__device__ __forceinline__ void compute_wsum2(const float* __restrict__ W,
                                              int lane, int wave, float* dst) {
    float s0 = 0.f, s1 = 0.f, s2 = 0.f;
    #pragma unroll
    for (int k = 0; k < 12; ++k) {
        const float* rw = W + (size_t)(D + lane + 64 * k) * NC;
        s0 += rw[wave];
        s1 += rw[wave + 4];
        if (wave == 0) s2 += rw[8];
    }
    s0 = wave_reduce_add(s0);
    s1 = wave_reduce_add(s1);
    s2 = wave_reduce_add(s2);
    if (lane == 63) {
        dst[wave]     = s0;
        dst[wave + 4] = s1;
        if (wave == 0) dst[8] = s2;
    }
}

// FMA one 4-dim chunk: v = h values for dims d..d+3; wk[j][p] = W'[d+j] column
// pair p (cols 2p,2p+1; p=4 -> {col8, ones}).
__device__ __forceinline__ void fma4(v2f (&acc)[5], float4 v,
                                     const v2f (&wk)[4][5]) {
    const float vv[4] = {v.x, v.y, v.z, v.w};
    #pragma unroll
    for (int j = 0; j < 4; ++j) {
        const v2f b = {vv[j], vv[j]};
        #pragma unroll
        for (int p = 0; p < 5; ++p)
            acc[p] = __builtin_elementwise_fma(b, wk[j][p], acc[p]);
    }
}

// ---------------------------------------------------------------------------
// Row pass (unchanged from round 4 — at/near the h-read roofline):
// wave per row, 8 rows/wave, 2-row compute, depth-1 prefetch.
// Writes 9 dots -> out, row mean -> means[].  No atomics.
// ---------------------------------------------------------------------------
__global__ __launch_bounds__(TPB, 2) void row_kernel(
    const float* __restrict__ h, const float* __restrict__ W,
    float* __restrict__ means, float* __restrict__ out)
{
    const int lane = threadIdx.x & 63;
    const int wave = threadIdx.x >> 6;
    const int base = (blockIdx.x * 4 + wave) * RPW;

    v2f wf[3][4][5];
    #pragma unroll
    for (int k = 0; k < 3; ++k) {
        const float4* wp = (const float4*)W + (size_t)(lane + 64 * k) * 9;
        float w36[36];
        #pragma unroll
        for (int i = 0; i < 9; ++i) {
            float4 v = wp[i];
            w36[4*i+0] = v.x; w36[4*i+1] = v.y; w36[4*i+2] = v.z; w36[4*i+3] = v.w;
        }
        #pragma unroll
        for (int j = 0; j < 4; ++j) {
            #pragma unroll
            for (int p = 0; p < 4; ++p)
                wf[k][j][p] = (v2f){w36[j*9 + 2*p], w36[j*9 + 2*p + 1]};
            wf[k][j][4] = (v2f){w36[j*9 + 8], 1.0f};
        }
    }

    const float4* hb = (const float4*)h + (size_t)base * (D / 4) + lane;
#define LDROW(rr, V0, V1, V2)                                                  \
    do { const float4* hp_ = hb + (size_t)(rr) * (D / 4);                      \
         V0 = hp_[0]; V1 = hp_[64]; V2 = hp_[128]; } while (0)

    float4 A0, A1, A2, B0, B1, B2;
    LDROW(0, A0, A1, A2);
    LDROW(1, B0, B1, B2);

    #pragma unroll
    for (int rp = 0; rp < RPW / 2; ++rp) {
        float4 N0, N1, N2, M0, M1, M2;
        if (rp < RPW / 2 - 1) {
            LDROW(2 * rp + 2, N0, N1, N2);
            LDROW(2 * rp + 3, M0, M1, M2);
        }
        const int rA = base + 2 * rp, rB = rA + 1;

        v2f accA[5], accB[5];
        #pragma unroll
        for (int p = 0; p < 5; ++p) {
            accA[p] = (v2f){0.f, 0.f};
            accB[p] = (v2f){0.f, 0.f};
        }
        fma4(accA, A0, wf[0]); fma4(accA, A1, wf[1]); fma4(accA, A2, wf[2]);
        fma4(accB, B0, wf[0]); fma4(accB, B1, wf[1]); fma4(accB, B2, wf[2]);

        float ra[10] = {accA[0].x, accA[0].y, accA[1].x, accA[1].y, accA[2].x,
                        accA[2].y, accA[3].x, accA[3].y, accA[4].x, accA[4].y};
        float rb[10] = {accB[0].x, accB[0].y, accB[1].x, accB[1].y, accB[2].x,
                        accB[2].y, accB[3].x, accB[3].y, accB[4].x, accB[4].y};
        #pragma unroll
        for (int t = 0; t < 10; ++t) {
            ra[t] = wave_reduce_add(ra[t]);
            rb[t] = wave_reduce_add(rb[t]);
        }

        if (lane == 63) {
            float* oA = out + (size_t)rA * NC;
            float* oB = out + (size_t)rB * NC;
            #pragma unroll
            for (int c = 0; c < 9; ++c) { oA[c] = ra[c]; oB[c] = rb[c]; }
            means[rA] = ra[9] * (1.f / 768.f);
            means[rB] = rb[9] * (1.f / 768.f);
        }

        if (rp < RPW / 2 - 1) {
            A0 = N0; A1 = N1; A2 = N2;
            B0 = M0; B1 = M1; B2 = M2;
        }
    }
#undef LDROW
}

// ---------------------------------------------------------------------------
// Finalize (restructured for latency): 512 blocks x 1024 threads; block b owns
// vocab slice [b*60, b*60+60).
//   scan 1: int4/float4 vectorized, UNCONDITIONAL means load (no dependent
//           branch before the load), 4 iterations/thread -> LDS sum/cnt.
//   scan 2: int4 ids; matching rows RMW out[row,:] (expected <=1 match/thread).
// ---------------------------------------------------------------------------
__global__ __launch_bounds__(TPB_FIN) void finalize_kernel(
    const int* __restrict__ ids, const float* __restrict__ means,
    const float* __restrict__ W, const float* __restrict__ bias,
    float* __restrict__ out)
{
    __shared__ float s_sum[SLICE];
    __shared__ float s_cnt[SLICE];
    __shared__ float s_wsum2[NC];

    const int tid  = threadIdx.x;
    const int lane = tid & 63;
    const int wave = tid >> 6;
    const int lo   = blockIdx.x * SLICE;

    if (tid < SLICE) { s_sum[tid] = 0.f; s_cnt[tid] = 0.f; }
    if (wave < 4) compute_wsum2(W, lane, wave, s_wsum2);
    __syncthreads();

    const int4*   ids4   = (const int4*)ids;
    const float4* means4 = (const float4*)means;

    // ---- scan 1: build slice sums/counts.  4 iterations, loads pipelined.
    #pragma unroll
    for (int q = tid; q < NROWS / 4; q += TPB_FIN) {
        const int4   i4 = ids4[q];
        const float4 m4 = means4[q];
        const int k0 = i4.x - lo, k1 = i4.y - lo, k2 = i4.z - lo, k3 = i4.w - lo;
        if ((unsigned)k0 < (unsigned)SLICE) { atomicAdd(&s_sum[k0], m4.x); atomicAdd(&s_cnt[k0], 1.f); }
        if ((unsigned)k1 < (unsigned)SLICE) { atomicAdd(&s_sum[k1], m4.y); atomicAdd(&s_cnt[k1], 1.f); }
        if ((unsigned)k2 < (unsigned)SLICE) { atomicAdd(&s_sum[k2], m4.z); atomicAdd(&s_cnt[k2], 1.f); }
        if ((unsigned)k3 < (unsigned)SLICE) { atomicAdd(&s_sum[k3], m4.w); atomicAdd(&s_cnt[k3], 1.f); }
    }
    __syncthreads();

    // sums -> means (one divide per slice entry, not per match)
    if (tid < SLICE) s_sum[tid] = s_sum[tid] / fmaxf(s_cnt[tid], 1.f);
    __syncthreads();

    // hoist wsum2/bias
    float wv[NC], bv[NC];
    #pragma unroll
    for (int c = 0; c < NC; ++c) { wv[c] = s_wsum2[c]; bv[c] = bias[c]; }

    // ---- scan 2: apply to this slice's rows.
    #pragma unroll
    for (int q = tid; q < NROWS / 4; q += TPB_FIN) {
        const int4 i4 = ids4[q];
        const int kk[4] = {i4.x - lo, i4.y - lo, i4.z - lo, i4.w - lo};
        #pragma unroll
        for (int j = 0; j < 4; ++j) {
            if ((unsigned)kk[j] < (unsigned)SLICE) {
                const float ctx = s_sum[kk[j]];
                float* op = out + (size_t)(4 * q + j) * NC;
                #pragma unroll
                for (int c = 0; c < NC; ++c)
                    op[c] += fmaf(ctx, wv[c], bv[c]);
            }
        }
    }
}

extern "C" void kernel_launch(void* const* d_in, const int* in_sizes, int n_in,
                              void* d_out, int out_size, void* d_ws, size_t ws_size,
                              hipStream_t stream) {
    const int*   ids = (const int*)  d_in[0];  // [32,512] int32
    const float* h   = (const float*)d_in[1];  // [32,512,768] f32
    const float* W   = (const float*)d_in[2];  // [1536,9] f32
    const float* b   = (const float*)d_in[3];  // [9] f32
    float* out   = (float*)d_out;              // [32,512,9] f32
    float* means = (float*)d_ws;               // [16384] f32

    row_kernel<<<G_ROW, TPB, 0, stream>>>(h, W, means, out);
    finalize_kernel<<<G_FIN, TPB_FIN, 0, stream>>>(ids, means, W, b, out);
}

// Round 6
// 25.757 us; speedup vs baseline: 2.1828x; 1.0698x over previous
//
#include <hip/hip_runtime.h>

#define VOCAB 30522
#define D     768
#define NC    9
#define NROWS 16384          // 32*512
#define TPB   256

#define G_ROW 512            // 4 waves/block * 8 rows/wave * 512 = 16384 rows
#define RPW   8

#define G_FIN 576            // 576*256 = 147456 = NROWS*NC exactly

typedef float v2f __attribute__((ext_vector_type(2)));

// Workspace (floats): seg_sum[VOCAB] | seg_cnt[VOCAB] | wsum2[16]
// = 244240 bytes (ws_size >= 834064 proven in round 1).

// ---------------------------------------------------------------------------
// Full-wave (64-lane) sum via DPP — pure VALU. Result valid in lane 63.
// (Sequence numerically validated rounds 2-5.)
// ---------------------------------------------------------------------------
__device__ __forceinline__ float wave_reduce_add(float x) {
#define DPP_STEP(ctrl)                                                         \
    do {                                                                       \
        int t_ = __builtin_amdgcn_update_dpp(0, __float_as_int(x), (ctrl),     \
                                             0xf, 0xf, true);                  \
        x += __int_as_float(t_);                                               \
    } while (0)
    DPP_STEP(0x111); // row_shr:1
    DPP_STEP(0x112); // row_shr:2
    DPP_STEP(0x114); // row_shr:4
    DPP_STEP(0x118); // row_shr:8
    DPP_STEP(0x142); // row_bcast:15
    DPP_STEP(0x143); // row_bcast:31 -> lane63 = total
#undef DPP_STEP
    return x;
}

// wsum2[c] = sum_{d>=768} W[d,c].  4 waves; lane-63 writes.
__device__ __forceinline__ void compute_wsum2(const float* __restrict__ W,
                                              int lane, int wave, float* dst) {
    float s0 = 0.f, s1 = 0.f, s2 = 0.f;
    #pragma unroll
    for (int k = 0; k < 12; ++k) {
        const float* rw = W + (size_t)(D + lane + 64 * k) * NC;
        s0 += rw[wave];
        s1 += rw[wave + 4];
        if (wave == 0) s2 += rw[8];
    }
    s0 = wave_reduce_add(s0);
    s1 = wave_reduce_add(s1);
    s2 = wave_reduce_add(s2);
    if (lane == 63) {
        dst[wave]     = s0;
        dst[wave + 4] = s1;
        if (wave == 0) dst[8] = s2;
    }
}

// ---------------------------------------------------------------------------
// Setup: zero seg tables (15261 float4) + wsum2 (last block).
// ---------------------------------------------------------------------------
__global__ __launch_bounds__(TPB) void setup_kernel(const float* __restrict__ W,
                                                    float* __restrict__ seg,
                                                    float* __restrict__ wsum2) {
    const int gid = blockIdx.x * TPB + threadIdx.x;
    if (gid < (2 * VOCAB + 3) / 4)
        ((float4*)seg)[gid] = make_float4(0.f, 0.f, 0.f, 0.f);
    if (blockIdx.x == gridDim.x - 1)
        compute_wsum2(W, threadIdx.x & 63, threadIdx.x >> 6, wsum2);
}

// FMA one 4-dim chunk: v = h values for dims d..d+3; wk[j][p] = W'[d+j] column
// pair p (cols 2p,2p+1; p=4 -> {col8, ones}).
__device__ __forceinline__ void fma4(v2f (&acc)[5], float4 v,
                                     const v2f (&wk)[4][5]) {
    const float vv[4] = {v.x, v.y, v.z, v.w};
    #pragma unroll
    for (int j = 0; j < 4; ++j) {
        const v2f b = {vv[j], vv[j]};
        #pragma unroll
        for (int p = 0; p < 5; ++p)
            acc[p] = __builtin_elementwise_fma(b, wk[j][p], acc[p]);
    }
}

// ---------------------------------------------------------------------------
// Row pass (streaming structure unchanged from rounds 4-5 — at the h-read
// floor): wave per row, 8 rows/wave, 2-row compute, depth-1 prefetch.
// Lane 63: 9 dots -> out, row mean -> global atomics into seg tables.
// ---------------------------------------------------------------------------
__global__ __launch_bounds__(TPB, 2) void row_kernel(
    const float* __restrict__ h, const float* __restrict__ W,
    const int* __restrict__ ids, float* __restrict__ seg,
    float* __restrict__ out)
{
    const int lane = threadIdx.x & 63;
    const int wave = threadIdx.x >> 6;
    const int base = (blockIdx.x * 4 + wave) * RPW;

    v2f wf[3][4][5];
    #pragma unroll
    for (int k = 0; k < 3; ++k) {
        const float4* wp = (const float4*)W + (size_t)(lane + 64 * k) * 9;
        float w36[36];
        #pragma unroll
        for (int i = 0; i < 9; ++i) {
            float4 v = wp[i];
            w36[4*i+0] = v.x; w36[4*i+1] = v.y; w36[4*i+2] = v.z; w36[4*i+3] = v.w;
        }
        #pragma unroll
        for (int j = 0; j < 4; ++j) {
            #pragma unroll
            for (int p = 0; p < 4; ++p)
                wf[k][j][p] = (v2f){w36[j*9 + 2*p], w36[j*9 + 2*p + 1]};
            wf[k][j][4] = (v2f){w36[j*9 + 8], 1.0f};
        }
    }

    const float4* hb = (const float4*)h + (size_t)base * (D / 4) + lane;
#define LDROW(rr, V0, V1, V2)                                                  \
    do { const float4* hp_ = hb + (size_t)(rr) * (D / 4);                      \
         V0 = hp_[0]; V1 = hp_[64]; V2 = hp_[128]; } while (0)

    float4 A0, A1, A2, B0, B1, B2;
    LDROW(0, A0, A1, A2);
    LDROW(1, B0, B1, B2);

    #pragma unroll
    for (int rp = 0; rp < RPW / 2; ++rp) {
        float4 N0, N1, N2, M0, M1, M2;
        if (rp < RPW / 2 - 1) {
            LDROW(2 * rp + 2, N0, N1, N2);
            LDROW(2 * rp + 3, M0, M1, M2);
        }
        const int rA = base + 2 * rp, rB = rA + 1;

        v2f accA[5], accB[5];
        #pragma unroll
        for (int p = 0; p < 5; ++p) {
            accA[p] = (v2f){0.f, 0.f};
            accB[p] = (v2f){0.f, 0.f};
        }
        fma4(accA, A0, wf[0]); fma4(accA, A1, wf[1]); fma4(accA, A2, wf[2]);
        fma4(accB, B0, wf[0]); fma4(accB, B1, wf[1]); fma4(accB, B2, wf[2]);

        float ra[10] = {accA[0].x, accA[0].y, accA[1].x, accA[1].y, accA[2].x,
                        accA[2].y, accA[3].x, accA[3].y, accA[4].x, accA[4].y};
        float rb[10] = {accB[0].x, accB[0].y, accB[1].x, accB[1].y, accB[2].x,
                        accB[2].y, accB[3].x, accB[3].y, accB[4].x, accB[4].y};
        #pragma unroll
        for (int t = 0; t < 10; ++t) {
            ra[t] = wave_reduce_add(ra[t]);
            rb[t] = wave_reduce_add(rb[t]);
        }

        if (lane == 63) {
            float* oA = out + (size_t)rA * NC;
            float* oB = out + (size_t)rB * NC;
            #pragma unroll
            for (int c = 0; c < 9; ++c) { oA[c] = ra[c]; oB[c] = rb[c]; }
            const int idA = ids[rA];
            const int idB = ids[rB];
            atomicAdd(seg + idA,         ra[9] * (1.f / 768.f));
            atomicAdd(seg + VOCAB + idA, 1.f);
            atomicAdd(seg + idB,         rb[9] * (1.f / 768.f));
            atomicAdd(seg + VOCAB + idB, 1.f);
        }

        if (rp < RPW / 2 - 1) {
            A0 = N0; A1 = N1; A2 = N2;
            B0 = M0; B1 = M1; B2 = M2;
        }
    }
#undef LDROW
}

// ---------------------------------------------------------------------------
// Finalize: one thread per output element (no scans, no barriers, no LDS).
// out[e] += (seg_sum[id]/max(cnt,1)) * wsum2[c] + bias[c]
// ---------------------------------------------------------------------------
__global__ __launch_bounds__(TPB) void finalize_kernel(
    const int* __restrict__ ids, const float* __restrict__ seg,
    const float* __restrict__ wsum2, const float* __restrict__ bias,
    float* __restrict__ out)
{
    const int e   = blockIdx.x * TPB + threadIdx.x;  // grid sized exactly
    const int row = e / NC;
    const int c   = e - row * NC;
    const int id  = ids[row];
    const float s   = seg[id];
    const float n   = seg[VOCAB + id];
    const float ctx = s / fmaxf(n, 1.f);
    out[e] += fmaf(ctx, wsum2[c], bias[c]);
}

extern "C" void kernel_launch(void* const* d_in, const int* in_sizes, int n_in,
                              void* d_out, int out_size, void* d_ws, size_t ws_size,
                              hipStream_t stream) {
    const int*   ids = (const int*)  d_in[0];  // [32,512] int32
    const float* h   = (const float*)d_in[1];  // [32,512,768] f32
    const float* W   = (const float*)d_in[2];  // [1536,9] f32
    const float* b   = (const float*)d_in[3];  // [9] f32
    float* out = (float*)d_out;                // [32,512,9] f32

    float* seg   = (float*)d_ws;               // [2*VOCAB]
    float* wsum2 = seg + 2 * VOCAB;            // [16]

    setup_kernel<<<60, TPB, 0, stream>>>(W, seg, wsum2);
    row_kernel<<<G_ROW, TPB, 0, stream>>>(h, W, ids, seg, out);
    finalize_kernel<<<G_FIN, TPB, 0, stream>>>(ids, seg, wsum2, b, out);
}